// Round 19
// baseline (172.416 us; speedup 1.0000x reference)
//
#include <hip/hip_runtime.h>
#include <hip/hip_bf16.h>
#include <stdint.h>

#define NQ 2048
#define NKV 2048
#define DIM 1024
#define INNER 1024
#define HEADS 16
#define DH 64
#define BATCH 2

typedef float f32x4 __attribute__((ext_vector_type(4)));
typedef float f32x16 __attribute__((ext_vector_type(16)));
typedef __bf16 bf16x8 __attribute__((ext_vector_type(8)));
typedef unsigned int u32x4 __attribute__((ext_vector_type(4)));

__device__ inline ushort f2b(float f) {
    uint32_t u = __builtin_bit_cast(uint32_t, f);
    u += 0x7fff + ((u >> 16) & 1);   // round-to-nearest-even
    return (ushort)(u >> 16);
}

__device__ inline uint pkbf16(float lo, float hi) {
    __hip_bfloat162 h = __float22bfloat162_rn(make_float2(lo, hi));
    uint r;
    __builtin_memcpy(&r, &h, 4);   // low 16 = bf16(lo), high 16 = bf16(hi)
    return r;
}

__device__ __forceinline__ void gload16(const void* g, void* lds) {
    __builtin_amdgcn_global_load_lds(
        (const __attribute__((address_space(1))) unsigned int*)g,
        (__attribute__((address_space(3))) unsigned int*)lds, 16, 0, 0);
}

// ---------------- fused prep: z<4 -> weight transpose+cvt slices; z==4 -> x/ctx convert ----------------
__global__ void prep(const float* __restrict__ x, const float* __restrict__ ctx,
                     const float* __restrict__ Wq, const float* __restrict__ Wkv,
                     const float* __restrict__ Wout,
                     ushort* __restrict__ xb, ushort* __restrict__ cb,
                     ushort* __restrict__ Wqt, ushort* __restrict__ Wkvt,
                     ushort* __restrict__ Woutt) {
    int z = blockIdx.z;
    if (z < 4) {
        __shared__ ushort tile[32][33];
        const float* src; ushort* dst; int C;
        if (z == 0)      { src = Wq;          dst = Wqt;                C = 1024; }
        else if (z == 1) { src = Wkv;         dst = Wkvt;               C = 2048; }
        else if (z == 2) { src = Wkv + 1024;  dst = Wkvt + 1024 * 1024; C = 2048; }
        else             { src = Wout;        dst = Woutt;              C = 1024; }
        int c0 = blockIdx.x * 32, r0 = blockIdx.y * 32;
        int tx = threadIdx.x, ty = threadIdx.y;   // 32 x 8
#pragma unroll
        for (int i = 0; i < 4; i++)
            tile[ty + i * 8][tx] = f2b(src[(size_t)(r0 + ty + i * 8) * C + c0 + tx]);
        __syncthreads();
#pragma unroll
        for (int i = 0; i < 4; i++)
            dst[(size_t)(c0 + ty + i * 8) * 1024 + r0 + tx] = tile[tx][ty + i * 8];
    } else {
        const int n4 = (BATCH * NQ * DIM) / 4;   // float4 count per tensor
        int fb = blockIdx.y * 32 + blockIdx.x;   // 0..1023
        int t = threadIdx.y * 32 + threadIdx.x;  // 0..255
        for (int i = fb * 256 + t; i < 2 * n4; i += 1024 * 256) {
            float4 v;
            if (i < n4) v = ((const float4*)x)[i];
            else        v = ((const float4*)ctx)[i - n4];
            ushort4 o;
            o.x = f2b(v.x); o.y = f2b(v.y); o.z = f2b(v.z); o.w = f2b(v.w);
            if (i < n4) ((ushort4*)xb)[i] = o;
            else        ((ushort4*)cb)[i - n4] = o;
        }
    }
}

// ---------------- fused q/kv GEMM v2: 384 blocks of 256x128, 8 waves, triple-buffer 2-deep ----------------
// swz < 128: qb = xb @ Wqt^T * qscale
// swz >= 128: kv = cb @ Wkvt^T; n<1024 -> kb row-major; n>=1024 -> vtb[b][h][d][kv] via LDS transpose
__global__ __launch_bounds__(512, 4) void gemm_qkv(const ushort* __restrict__ xb, const ushort* __restrict__ cb,
                                                   const ushort* __restrict__ Wqt, const ushort* __restrict__ Wkvt,
                                                   ushort* __restrict__ qb, ushort* __restrict__ kb,
                                                   ushort* __restrict__ vtb, float qscale) {
    constexpr int K = 1024, NT = 32;
    __shared__ ushort lds[36864];   // 72KB: 3 bufs x (A 16KB + B 8KB); v-epilogue C^T [128][256] reuses
    int flat = blockIdx.x;
    int swz = (flat & 7) * 48 + (flat >> 3);      // XCD-chunked, bijective (384 % 8 == 0)
    bool isq = swz < 128;
    const ushort *A, *Bt;
    int m0, n0;
    if (isq) { A = xb; Bt = Wqt;  m0 = (swz >> 3) * 256;  n0 = (swz & 7) * 128; }
    else     { int b2 = swz - 128; A = cb; Bt = Wkvt; m0 = (b2 >> 4) * 256; n0 = (b2 & 15) * 128; }
    int t = threadIdx.x, l = t & 63, w = t >> 6;   // 8 waves
    int wm = w >> 1, wn = w & 1;                   // 4M x 2N wave grid, wave tile 64x64
    int lg = l >> 4, lc = l & 15;
    f32x4 acc[4][4] = {};

    auto stage = [&](int buf, int k0) {
#pragma unroll
        for (int i = 0; i < 2; i++) {             // A: 256x32 = 16KB, layout [kc4][row256][8]
            int d = i * 8192 + t * 16;            // byte offset in A region
            int kc = d >> 12, row = (d >> 4) & 255;
            gload16(A + (size_t)(m0 + row) * K + k0 + kc * 8, &lds[buf * 12288 + (d >> 1)]);
        }
        {                                          // B: 128x32 = 8KB, layout [kc4][row128][8]
            int kc = t >> 7, row = t & 127;
            gload16(Bt + (size_t)(n0 + row) * K + k0 + kc * 8, &lds[buf * 12288 + 8192 + t * 8]);
        }
    };

    stage(0, 0);
    stage(1, 32);
    for (int tt = 0; tt < NT; ++tt) {
        int cur = tt % 3;
        if (tt + 2 < NT) {
            stage((tt + 2) % 3, (tt + 2) * 32);   // 2-deep prefetch, stays in flight
            asm volatile("s_waitcnt vmcnt(6)" ::: "memory");   // oldest 3 (cur tile) done
        } else if (tt + 1 < NT) {
            asm volatile("s_waitcnt vmcnt(3)" ::: "memory");
        } else {
            asm volatile("s_waitcnt vmcnt(0)" ::: "memory");
        }
        __builtin_amdgcn_s_barrier();
        asm volatile("" ::: "memory");
        bf16x8 af[4], bf[4];
#pragma unroll
        for (int mi = 0; mi < 4; mi++)
            af[mi] = *(const bf16x8*)&lds[cur * 12288 + (lg * 256 + wm * 64 + mi * 16 + lc) * 8];
#pragma unroll
        for (int ni = 0; ni < 4; ni++)
            bf[ni] = *(const bf16x8*)&lds[cur * 12288 + 8192 + (lg * 128 + wn * 64 + ni * 16 + lc) * 8];
        __builtin_amdgcn_s_setprio(1);
#pragma unroll
        for (int mi = 0; mi < 4; mi++)
#pragma unroll
            for (int ni = 0; ni < 4; ni++)
                acc[mi][ni] = __builtin_amdgcn_mfma_f32_16x16x32_bf16(af[mi], bf[ni], acc[mi][ni], 0, 0, 0);
        __builtin_amdgcn_s_setprio(0);
        asm volatile("s_waitcnt lgkmcnt(0)" ::: "memory");
        __builtin_amdgcn_s_barrier();
        asm volatile("" ::: "memory");
    }
    if (isq) {
#pragma unroll
        for (int mi = 0; mi < 4; mi++)
#pragma unroll
            for (int ni = 0; ni < 4; ni++)
#pragma unroll
                for (int r = 0; r < 4; r++) {
                    int m = m0 + wm * 64 + mi * 16 + lg * 4 + r;
                    int n = n0 + wn * 64 + ni * 16 + lc;
                    qb[(size_t)m * 1024 + n] = f2b(acc[mi][ni][r] * qscale);
                }
    } else if (n0 < 1024) {      // k half: row-major
#pragma unroll
        for (int mi = 0; mi < 4; mi++)
#pragma unroll
            for (int ni = 0; ni < 4; ni++)
#pragma unroll
                for (int r = 0; r < 4; r++) {
                    int m = m0 + wm * 64 + mi * 16 + lg * 4 + r;
                    int n = n0 + wn * 64 + ni * 16 + lc;
                    kb[(size_t)m * 1024 + n] = f2b(acc[mi][ni][r]);
                }
    } else {                     // v half: LDS C^T [n128][m256] (XOR-swizzled m-chunks) -> coalesced vtb
        int b = m0 >> 11, kv0 = m0 & 2047;
        int nb0 = n0 - 1024;
#pragma unroll
        for (int mi = 0; mi < 4; mi++)
#pragma unroll
            for (int ni = 0; ni < 4; ni++) {
                int nl = wn * 64 + ni * 16 + lc;
                int mlb = (wm * 64 + mi * 16 + lg * 4) ^ ((nl & 7) << 3);
                ushort4 pk;
                pk.x = f2b(acc[mi][ni][0]); pk.y = f2b(acc[mi][ni][1]);
                pk.z = f2b(acc[mi][ni][2]); pk.w = f2b(acc[mi][ni][3]);
                *(ushort4*)&lds[nl * 256 + mlb] = pk;
            }
        __syncthreads();
#pragma unroll
        for (int p = 0; p < 8; p++) {
            int idx = p * 512 + t;            // 0..4095
            int nl = idx >> 5, mc = idx & 31; // n-local, 8-elem kv chunk
            u32x4 v = *(u32x4*)&lds[nl * 256 + (mc ^ (nl & 7)) * 8];
            int h = (nb0 + nl) >> 6, d = (nb0 + nl) & 63;
            *(u32x4*)&vtb[(((size_t)b * HEADS + h) * DH + d) * (size_t)NKV + kv0 + mc * 8] = v;
        }
    }
}

// ---------------- out-proj GEMM: 256 blocks of 128x128, triple-buffer 2-deep, f32 out + bias ----------------
__global__ __launch_bounds__(256) void gemm_out(const ushort* __restrict__ A, const ushort* __restrict__ Bt,
                                                float* __restrict__ C0, const float* __restrict__ bias) {
    constexpr int K = 1024, NT = 32;
    __shared__ ushort lds[24576];
    int flat = blockIdx.x;
    int swz = (flat & 7) * 32 + (flat >> 3);      // XCD-chunked (256 % 8 == 0)
    int m0 = (swz >> 3) * 128, n0 = (swz & 7) * 128;
    int t = threadIdx.x, l = t & 63, w = t >> 6;
    int wr = w >> 1, wc = w & 1;
    int lg = l >> 4, lc = l & 15;
    f32x4 acc[4][4] = {};

    auto stage = [&](int buf, int k0) {
#pragma unroll
        for (int i = 0; i < 2; i++) {
            int s = w + i * 4;
            gload16(A + (size_t)(m0 + (s & 1) * 64 + l) * K + k0 + (s >> 1) * 8, &lds[buf * 8192 + s * 512]);
            gload16(Bt + (size_t)(n0 + (s & 1) * 64 + l) * K + k0 + (s >> 1) * 8, &lds[buf * 8192 + 4096 + s * 512]);
        }
    };

    stage(0, 0);
    stage(1, 32);
    for (int tt = 0; tt < NT; ++tt) {
        int cur = tt % 3;
        if (tt + 2 < NT) {
            stage((tt + 2) % 3, (tt + 2) * 32);
            asm volatile("s_waitcnt vmcnt(8)" ::: "memory");
        } else if (tt + 1 < NT) {
            asm volatile("s_waitcnt vmcnt(4)" ::: "memory");
        } else {
            asm volatile("s_waitcnt vmcnt(0)" ::: "memory");
        }
        __builtin_amdgcn_s_barrier();
        asm volatile("" ::: "memory");
        bf16x8 af[4], bf[4];
#pragma unroll
        for (int mi = 0; mi < 4; mi++)
            af[mi] = *(const bf16x8*)&lds[cur * 8192 + (lg * 128 + wr * 64 + mi * 16 + lc) * 8];
#pragma unroll
        for (int ni = 0; ni < 4; ni++)
            bf[ni] = *(const bf16x8*)&lds[cur * 8192 + 4096 + (lg * 128 + wc * 64 + ni * 16 + lc) * 8];
        __builtin_amdgcn_s_setprio(1);
#pragma unroll
        for (int mi = 0; mi < 4; mi++)
#pragma unroll
            for (int ni = 0; ni < 4; ni++)
                acc[mi][ni] = __builtin_amdgcn_mfma_f32_16x16x32_bf16(af[mi], bf[ni], acc[mi][ni], 0, 0, 0);
        __builtin_amdgcn_s_setprio(0);
        asm volatile("s_waitcnt lgkmcnt(0)" ::: "memory");
        __builtin_amdgcn_s_barrier();
        asm volatile("" ::: "memory");
    }
#pragma unroll
    for (int mi = 0; mi < 4; mi++)
#pragma unroll
        for (int ni = 0; ni < 4; ni++)
#pragma unroll
            for (int r = 0; r < 4; r++) {
                int m = m0 + wr * 64 + mi * 16 + lg * 4 + r;
                int n = n0 + wc * 64 + ni * 16 + lc;
                C0[(size_t)m * 1024 + n] = acc[mi][ni][r] + bias[n];
            }
}

// ---------------- flash attention v11: 32x32 MFMA, in-reg P, 3-buffer K/V ----------------
// QBLK=128 (4 waves x 32 q), KVBLK=64, schedule: vmcnt(4); barrier; stage(tt+2).
// Q frags direct from global. Swapped QK^T; P via cvt_pk + permlane32_swap. qb pre-scaled 0.125*log2e.
__global__ __launch_bounds__(256, 3) void attn9(const ushort* __restrict__ qb, const ushort* __restrict__ kb,
                                                const ushort* __restrict__ vtb, ushort* __restrict__ ob) {
    __shared__ ushort Ks[3][4096];       // [dc8][kv64][8] 8KB x3
    __shared__ ushort Vs[3][4096];       // [kvc8][d64][8] 8KB x3
    int flat = blockIdx.x;
    int swz = (flat & 7) * 64 + (flat >> 3);           // XCD-chunked (512 % 8 == 0)
    int qt = swz & 15, h = (swz >> 4) & 15, b = swz >> 8;
    int t = threadIdx.x, l = t & 63, w = t >> 6;
    int ll = l & 31, hi = l >> 5;
    const ushort* Qg = qb + (size_t)b * NQ * INNER + h * DH;
    const ushort* Kg = kb + (size_t)b * NKV * INNER + h * DH;
    const ushort* Vg = vtb + (((size_t)b * HEADS + h) * DH) * NKV;
    int q0 = qt * 128;
    constexpr int NT2 = NKV / 64;        // 32

    // Q fragments direct from global (one-time): q col = w*32+ll, d rows = (dchunk*2+hi)*8..+8
    bf16x8 qf[4];
#pragma unroll
    for (int dchunk = 0; dchunk < 4; dchunk++) {
        int dc = dchunk * 2 + hi;
        qf[dchunk] = *(const bf16x8*)&Qg[(size_t)(q0 + w * 32 + ll) * INNER + dc * 8];
    }
    auto stageKV = [&](int buf, int kv0) {
#pragma unroll
        for (int i = 0; i < 2; i++) {
            int s = w + i * 4;
            gload16(Kg + (size_t)(kv0 + l) * INNER + s * 8, &Ks[buf][s * 512]);
            gload16(Vg + (size_t)l * NKV + kv0 + s * 8, &Vs[buf][s * 512]);
        }
    };
    stageKV(0, 0);
    stageKV(1, 64);

    f32x16 o0 = {}, o1 = {};             // O^T dblk 0/1: col q = w*32+ll, rows d per 32x32 D-layout
    float m_ = -1e30f, s_ = 0.f;
    f32x16 zf = {};

    for (int tt = 0; tt < NT2; ++tt) {
        int cur = tt % 3;
        if (tt + 1 < NT2) {
            asm volatile("s_waitcnt vmcnt(4)" ::: "memory");   // tile tt landed, tt+1 in flight
        } else {
            asm volatile("s_waitcnt vmcnt(0)" ::: "memory");
        }
        __builtin_amdgcn_s_barrier();     // all waves done reading buf (tt+2)%3 (last read at iter tt-1)
        asm volatile("" ::: "memory");
        if (tt + 2 < NT2) stageKV((tt + 2) % 3, (tt + 2) * 64);

        // QK^T: S^T[kv64][q32] via 2 kv-blocks x 4 d-chunks of mfma_32x32x16
        f32x16 st0 = zf, st1 = zf;
        __builtin_amdgcn_s_setprio(1);
#pragma unroll
        for (int dchunk = 0; dchunk < 4; dchunk++) {
            int dc = dchunk * 2 + hi;
            bf16x8 kf0 = *(const bf16x8*)&Ks[cur][(dc * 64 + ll) * 8];
            bf16x8 kf1 = *(const bf16x8*)&Ks[cur][(dc * 64 + 32 + ll) * 8];
            st0 = __builtin_amdgcn_mfma_f32_32x32x16_bf16(kf0, qf[dchunk], st0, 0, 0, 0);
            st1 = __builtin_amdgcn_mfma_f32_32x32x16_bf16(kf1, qf[dchunk], st1, 0, 0, 0);
        }
        __builtin_amdgcn_s_setprio(0);

        // in-register online softmax: lane owns q; kv rows split between lane l and l^32
        float mx;
        {
            f32x16 m01 = __builtin_elementwise_max(st0, st1);
            float a = fmaxf(fmaxf(m01[0], m01[1]), fmaxf(m01[2], m01[3]));
            float b2 = fmaxf(fmaxf(m01[4], m01[5]), fmaxf(m01[6], m01[7]));
            float c = fmaxf(fmaxf(m01[8], m01[9]), fmaxf(m01[10], m01[11]));
            float d = fmaxf(fmaxf(m01[12], m01[13]), fmaxf(m01[14], m01[15]));
            mx = fmaxf(fmaxf(a, b2), fmaxf(c, d));
        }
        mx = fmaxf(mx, __shfl_xor(mx, 32));
        if (!__all(mx - m_ <= 8.f)) {        // defer-max (T13)
            float mn2 = fmaxf(m_, mx);
            float fac = __builtin_amdgcn_exp2f(m_ - mn2);
            m_ = mn2; s_ *= fac; o0 *= fac; o1 *= fac;
        }
        float mn = m_;
#pragma unroll
        for (int r = 0; r < 16; r++) st0[r] = __builtin_amdgcn_exp2f(st0[r] - mn);
#pragma unroll
        for (int r = 0; r < 16; r++) st1[r] = __builtin_amdgcn_exp2f(st1[r] - mn);
        float rs;
        {
            f32x16 sm = st0 + st1;
            float a = (sm[0] + sm[1]) + (sm[2] + sm[3]);
            float b2 = (sm[4] + sm[5]) + (sm[6] + sm[7]);
            float c = (sm[8] + sm[9]) + (sm[10] + sm[11]);
            float d = (sm[12] + sm[13]) + (sm[14] + sm[15]);
            rs = (a + b2) + (c + d);
        }
        rs += __shfl_xor(rs, 32);
        s_ += rs;

        // P -> PV B-frags in registers: cvt_pk + permlane32_swap (proven layout)
        bf16x8 pb[4];
#pragma unroll
        for (int kvb = 0; kvb < 2; kvb++)
#pragma unroll
            for (int c = 0; c < 2; c++) {
                int base = c * 8;
                const f32x16& s0 = (kvb == 0) ? st0 : st1;
                uint a0 = pkbf16(s0[base + 0], s0[base + 1]);
                uint a1 = pkbf16(s0[base + 2], s0[base + 3]);
                uint b0 = pkbf16(s0[base + 4], s0[base + 5]);
                uint b1 = pkbf16(s0[base + 6], s0[base + 7]);
                asm volatile("v_permlane32_swap_b32 %0, %1" : "+v"(a0), "+v"(b0));
                asm volatile("v_permlane32_swap_b32 %0, %1" : "+v"(a1), "+v"(b1));
                u32x4 wrd = {a0, a1, b0, b1};
                pb[kvb * 2 + c] = __builtin_bit_cast(bf16x8, wrd);
            }

        // PV: O^T[d][q] += V^T-frag x P-frag over 4 kv-chunks
        __builtin_amdgcn_s_setprio(1);
#pragma unroll
        for (int kvchunk = 0; kvchunk < 4; kvchunk++) {
            int kvc = kvchunk * 2 + hi;
            bf16x8 vf0 = *(const bf16x8*)&Vs[cur][(kvc * 64 + ll) * 8];
            bf16x8 vf1 = *(const bf16x8*)&Vs[cur][(kvc * 64 + 32 + ll) * 8];
            o0 = __builtin_amdgcn_mfma_f32_32x32x16_bf16(vf0, pb[kvchunk], o0, 0, 0, 0);
            o1 = __builtin_amdgcn_mfma_f32_32x32x16_bf16(vf1, pb[kvchunk], o1, 0, 0, 0);
        }
        __builtin_amdgcn_s_setprio(0);
    }

    ushort* Og = ob + (size_t)b * NQ * INNER + h * DH;
    float inv = 1.f / s_;
    int q = q0 + w * 32 + ll;
#pragma unroll
    for (int rq = 0; rq < 4; rq++) {
        int d0 = 8 * rq + 4 * hi;
        uint2 pw;
        pw.x = pkbf16(o0[4 * rq + 0] * inv, o0[4 * rq + 1] * inv);
        pw.y = pkbf16(o0[4 * rq + 2] * inv, o0[4 * rq + 3] * inv);
        *(uint2*)&Og[(size_t)q * INNER + d0] = pw;
        uint2 pw1;
        pw1.x = pkbf16(o1[4 * rq + 0] * inv, o1[4 * rq + 1] * inv);
        pw1.y = pkbf16(o1[4 * rq + 2] * inv, o1[4 * rq + 3] * inv);
        *(uint2*)&Og[(size_t)q * INNER + 32 + d0] = pw1;
    }
}

extern "C" void kernel_launch(void* const* d_in, const int* in_sizes, int n_in,
                              void* d_out, int out_size, void* d_ws, size_t ws_size,
                              hipStream_t stream) {
    const float* x    = (const float*)d_in[0];
    const float* ctx  = (const float*)d_in[1];
    const float* Wq   = (const float*)d_in[2];
    const float* Wkv  = (const float*)d_in[3];
    const float* Wout = (const float*)d_in[4];
    const float* bout = (const float*)d_in[5];
    float* out = (float*)d_out;

    if (ws_size < (size_t)(56u << 20)) return;  // need 56MB scratch
    char* ws = (char*)d_ws;
    ushort* xb    = (ushort*)(ws);                 // 8MB
    ushort* cb    = (ushort*)(ws + (8u << 20));    // 8MB, dead after gemm_qkv
    ushort* ob    = (ushort*)(ws + (8u << 20));    // reuse cb slot
    ushort* qb    = (ushort*)(ws + (16u << 20));
    ushort* kb    = (ushort*)(ws + (24u << 20));
    ushort* vtb   = (ushort*)(ws + (32u << 20));   // v written directly transposed
    ushort* Wqt   = (ushort*)(ws + (48u << 20));
    ushort* Wkvt  = (ushort*)(ws + (50u << 20));
    ushort* Woutt = (ushort*)(ws + (54u << 20));

    prep<<<dim3(32, 32, 5), dim3(32, 8), 0, stream>>>(x, ctx, Wq, Wkv, Wout, xb, cb, Wqt, Wkvt, Woutt);
    // fused q-proj (scaled by 0.125*log2e) + kv-proj (v written transposed)
    gemm_qkv<<<384, 512, 0, stream>>>(xb, cb, Wqt, Wkvt, qb, kb, vtb, 0.125f * 1.44269504f);
    attn9<<<512, 256, 0, stream>>>(qb, kb, vtb, ob);
    gemm_out<<<256, 256, 0, stream>>>(ob, Woutt, out, bout);
}

// Round 20
// 165.176 us; speedup vs baseline: 1.0438x; 1.0438x over previous
//
#include <hip/hip_runtime.h>
#include <hip/hip_bf16.h>
#include <stdint.h>

#define NQ 2048
#define NKV 2048
#define DIM 1024
#define INNER 1024
#define HEADS 16
#define DH 64
#define BATCH 2

typedef float f32x4 __attribute__((ext_vector_type(4)));
typedef float f32x16 __attribute__((ext_vector_type(16)));
typedef __bf16 bf16x8 __attribute__((ext_vector_type(8)));
typedef unsigned int u32x4 __attribute__((ext_vector_type(4)));

__device__ inline ushort f2b(float f) {
    uint32_t u = __builtin_bit_cast(uint32_t, f);
    u += 0x7fff + ((u >> 16) & 1);   // round-to-nearest-even
    return (ushort)(u >> 16);
}

__device__ inline uint pkbf16(float lo, float hi) {
    __hip_bfloat162 h = __float22bfloat162_rn(make_float2(lo, hi));
    uint r;
    __builtin_memcpy(&r, &h, 4);   // low 16 = bf16(lo), high 16 = bf16(hi)
    return r;
}

__device__ __forceinline__ void gload16(const void* g, void* lds) {
    __builtin_amdgcn_global_load_lds(
        (const __attribute__((address_space(1))) unsigned int*)g,
        (__attribute__((address_space(3))) unsigned int*)lds, 16, 0, 0);
}

// ---------------- fused prep: z<4 -> weight transpose+cvt slices; z==4 -> x/ctx convert ----------------
__global__ void prep(const float* __restrict__ x, const float* __restrict__ ctx,
                     const float* __restrict__ Wq, const float* __restrict__ Wkv,
                     const float* __restrict__ Wout,
                     ushort* __restrict__ xb, ushort* __restrict__ cb,
                     ushort* __restrict__ Wqt, ushort* __restrict__ Wkvt,
                     ushort* __restrict__ Woutt) {
    int z = blockIdx.z;
    if (z < 4) {
        __shared__ ushort tile[32][33];
        const float* src; ushort* dst; int C;
        if (z == 0)      { src = Wq;          dst = Wqt;                C = 1024; }
        else if (z == 1) { src = Wkv;         dst = Wkvt;               C = 2048; }
        else if (z == 2) { src = Wkv + 1024;  dst = Wkvt + 1024 * 1024; C = 2048; }
        else             { src = Wout;        dst = Woutt;              C = 1024; }
        int c0 = blockIdx.x * 32, r0 = blockIdx.y * 32;
        int tx = threadIdx.x, ty = threadIdx.y;   // 32 x 8
#pragma unroll
        for (int i = 0; i < 4; i++)
            tile[ty + i * 8][tx] = f2b(src[(size_t)(r0 + ty + i * 8) * C + c0 + tx]);
        __syncthreads();
#pragma unroll
        for (int i = 0; i < 4; i++)
            dst[(size_t)(c0 + ty + i * 8) * 1024 + r0 + tx] = tile[tx][ty + i * 8];
    } else {
        const int n4 = (BATCH * NQ * DIM) / 4;   // float4 count per tensor
        int fb = blockIdx.y * 32 + blockIdx.x;   // 0..1023
        int t = threadIdx.y * 32 + threadIdx.x;  // 0..255
        for (int i = fb * 256 + t; i < 2 * n4; i += 1024 * 256) {
            float4 v;
            if (i < n4) v = ((const float4*)x)[i];
            else        v = ((const float4*)ctx)[i - n4];
            ushort4 o;
            o.x = f2b(v.x); o.y = f2b(v.y); o.z = f2b(v.z); o.w = f2b(v.w);
            if (i < n4) ((ushort4*)xb)[i] = o;
            else        ((ushort4*)cb)[i - n4] = o;
        }
    }
}

// ---------------- fused q/kv GEMM: 768 blocks of 128x128, K=1024, triple-buffer 2-deep prefetch ----------------
__global__ __launch_bounds__(256) void gemm_qkv(const ushort* __restrict__ xb, const ushort* __restrict__ cb,
                                                const ushort* __restrict__ Wqt, const ushort* __restrict__ Wkvt,
                                                ushort* __restrict__ qb, ushort* __restrict__ kb,
                                                ushort* __restrict__ vtb, float qscale) {
    constexpr int K = 1024, NT = 32;
    __shared__ ushort lds[24576];   // 48KB: 3 bufs x (A 8KB + B 8KB); v-epilogue tile [128][136] reuses
    int flat = blockIdx.x;
    int swz = (flat & 7) * 96 + (flat >> 3);      // XCD-chunked, bijective (768 % 8 == 0)
    bool isq = swz < 256;
    const ushort *A, *Bt;
    int m0, n0;
    if (isq) { A = xb; Bt = Wqt;  m0 = (swz >> 3) * 128;  n0 = (swz & 7) * 128; }
    else     { int b2 = swz - 256; A = cb; Bt = Wkvt; m0 = (b2 >> 4) * 128; n0 = (b2 & 15) * 128; }
    int t = threadIdx.x, l = t & 63, w = t >> 6;
    int wr = w >> 1, wc = w & 1;
    int lg = l >> 4, lc = l & 15;
    f32x4 acc[4][4] = {};

    auto stage = [&](int buf, int k0) {
#pragma unroll
        for (int i = 0; i < 2; i++) {
            int s = w + i * 4;
            gload16(A + (size_t)(m0 + (s & 1) * 64 + l) * K + k0 + (s >> 1) * 8, &lds[buf * 8192 + s * 512]);
            gload16(Bt + (size_t)(n0 + (s & 1) * 64 + l) * K + k0 + (s >> 1) * 8, &lds[buf * 8192 + 4096 + s * 512]);
        }
    };

    stage(0, 0);
    stage(1, 32);
    for (int tt = 0; tt < NT; ++tt) {
        int cur = tt % 3;
        if (tt + 2 < NT) {
            stage((tt + 2) % 3, (tt + 2) * 32);   // 2-deep prefetch, stays in flight
            asm volatile("s_waitcnt vmcnt(8)" ::: "memory");   // oldest 4 (cur tile) done
        } else if (tt + 1 < NT) {
            asm volatile("s_waitcnt vmcnt(4)" ::: "memory");
        } else {
            asm volatile("s_waitcnt vmcnt(0)" ::: "memory");
        }
        __builtin_amdgcn_s_barrier();
        asm volatile("" ::: "memory");
        bf16x8 af[4], bf[4];
#pragma unroll
        for (int mi = 0; mi < 4; mi++)
            af[mi] = *(const bf16x8*)&lds[cur * 8192 + (lg * 128 + wr * 64 + mi * 16 + lc) * 8];
#pragma unroll
        for (int ni = 0; ni < 4; ni++)
            bf[ni] = *(const bf16x8*)&lds[cur * 8192 + 4096 + (lg * 128 + wc * 64 + ni * 16 + lc) * 8];
        __builtin_amdgcn_s_setprio(1);
#pragma unroll
        for (int mi = 0; mi < 4; mi++)
#pragma unroll
            for (int ni = 0; ni < 4; ni++)
                acc[mi][ni] = __builtin_amdgcn_mfma_f32_16x16x32_bf16(af[mi], bf[ni], acc[mi][ni], 0, 0, 0);
        __builtin_amdgcn_s_setprio(0);
        asm volatile("s_waitcnt lgkmcnt(0)" ::: "memory");
        __builtin_amdgcn_s_barrier();
        asm volatile("" ::: "memory");
    }
    if (isq) {
#pragma unroll
        for (int mi = 0; mi < 4; mi++)
#pragma unroll
            for (int ni = 0; ni < 4; ni++)
#pragma unroll
                for (int r = 0; r < 4; r++) {
                    int m = m0 + wr * 64 + mi * 16 + lg * 4 + r;
                    int n = n0 + wc * 64 + ni * 16 + lc;
                    qb[(size_t)m * 1024 + n] = f2b(acc[mi][ni][r] * qscale);
                }
    } else if (n0 < 1024) {      // k half: row-major
#pragma unroll
        for (int mi = 0; mi < 4; mi++)
#pragma unroll
            for (int ni = 0; ni < 4; ni++)
#pragma unroll
                for (int r = 0; r < 4; r++) {
                    int m = m0 + wr * 64 + mi * 16 + lg * 4 + r;
                    int n = n0 + wc * 64 + ni * 16 + lc;
                    kb[(size_t)m * 1024 + n] = f2b(acc[mi][ni][r]);
                }
    } else {                     // v half: LDS transpose -> coalesced vtb[b][h][d][kv] stores
        int b = m0 >> 11, kv0 = m0 & 2047;
        int h0 = (n0 - 1024) >> 6;                // block covers heads h0, h0+1
#pragma unroll
        for (int mi = 0; mi < 4; mi++)
#pragma unroll
            for (int ni = 0; ni < 4; ni++)
#pragma unroll
                for (int r = 0; r < 4; r++) {
                    int ml = wr * 64 + mi * 16 + lg * 4 + r;    // kv-local 0..127
                    int nl = wc * 64 + ni * 16 + lc;            // n-local 0..127
                    lds[nl * 136 + ml] = f2b(acc[mi][ni][r]);
                }
        __syncthreads();
#pragma unroll
        for (int c = 0; c < 8; c++) {
            int idx = c * 256 + t;            // 0..2047
            int rrow = idx >> 4;              // n-local 0..127
            int chunk = idx & 15;             // 16B chunk along kv
            int h = h0 + (rrow >> 6), d = rrow & 63;
            u32x4 v = *(u32x4*)&lds[rrow * 136 + chunk * 8];
            *(u32x4*)&vtb[(((size_t)b * HEADS + h) * DH + d) * (size_t)NKV + kv0 + chunk * 8] = v;
        }
    }
}

// ---------------- out-proj GEMM: 512 blocks of 64x128, triple-buffer 2-deep, f32 out + bias ----------------
__global__ __launch_bounds__(256) void gemm_out(const ushort* __restrict__ A, const ushort* __restrict__ Bt,
                                                float* __restrict__ C0, const float* __restrict__ bias) {
    constexpr int K = 1024, NT = 32;
    __shared__ ushort lds[3][6144];   // per buf: A 64x32 (4KB) @0, B 128x32 (8KB) @2048
    int flat = blockIdx.x;
    int swz = (flat & 7) * 64 + (flat >> 3);      // XCD-chunked (512 % 8 == 0)
    int m0 = (swz >> 3) * 64, n0 = (swz & 7) * 128;
    int t = threadIdx.x, l = t & 63, w = t >> 6;
    int wr = w >> 1, wc = w & 1;
    int lg = l >> 4, lc = l & 15;
    f32x4 acc[2][4] = {};

    auto stage = [&](int buf, int k0) {
        gload16(A + (size_t)(m0 + l) * K + k0 + w * 8, &lds[buf][w * 512 + l * 8]);
#pragma unroll
        for (int i = 0; i < 2; i++) {
            int s = w + i * 4;
            gload16(Bt + (size_t)(n0 + (s & 1) * 64 + l) * K + k0 + (s >> 1) * 8, &lds[buf][2048 + s * 512]);
        }
    };

    stage(0, 0);
    stage(1, 32);
    for (int tt = 0; tt < NT; ++tt) {
        int cur = tt % 3;
        if (tt + 2 < NT) {
            stage((tt + 2) % 3, (tt + 2) * 32);
            asm volatile("s_waitcnt vmcnt(6)" ::: "memory");
        } else if (tt + 1 < NT) {
            asm volatile("s_waitcnt vmcnt(3)" ::: "memory");
        } else {
            asm volatile("s_waitcnt vmcnt(0)" ::: "memory");
        }
        __builtin_amdgcn_s_barrier();
        asm volatile("" ::: "memory");
        bf16x8 af[2], bf[4];
#pragma unroll
        for (int mi = 0; mi < 2; mi++)
            af[mi] = *(const bf16x8*)&lds[cur][(lg * 64 + wr * 32 + mi * 16 + lc) * 8];
#pragma unroll
        for (int ni = 0; ni < 4; ni++)
            bf[ni] = *(const bf16x8*)&lds[cur][2048 + (lg * 128 + wc * 64 + ni * 16 + lc) * 8];
        __builtin_amdgcn_s_setprio(1);
#pragma unroll
        for (int mi = 0; mi < 2; mi++)
#pragma unroll
            for (int ni = 0; ni < 4; ni++)
                acc[mi][ni] = __builtin_amdgcn_mfma_f32_16x16x32_bf16(af[mi], bf[ni], acc[mi][ni], 0, 0, 0);
        __builtin_amdgcn_s_setprio(0);
        asm volatile("s_waitcnt lgkmcnt(0)" ::: "memory");
        __builtin_amdgcn_s_barrier();
        asm volatile("" ::: "memory");
    }
#pragma unroll
    for (int mi = 0; mi < 2; mi++)
#pragma unroll
        for (int ni = 0; ni < 4; ni++)
#pragma unroll
            for (int r = 0; r < 4; r++) {
                int m = m0 + wr * 32 + mi * 16 + lg * 4 + r;
                int n = n0 + wc * 64 + ni * 16 + lc;
                C0[(size_t)m * 1024 + n] = acc[mi][ni][r] + bias[n];
            }
}

// ---------------- flash attention v8 (R15-proven): 32x32 MFMA, in-register P, 3-buffer K/V ----------------
// QBLK=128 (4 waves x 32 q each), KVBLK=64, triple-buffered K/V with 2-deep prefetch.
// Swapped QK^T: S^T[kv][q], lane owns q = w*32 + (l&31). NO P-LDS roundtrip. qb pre-scaled 0.125*log2e.
__global__ __launch_bounds__(256, 2) void attn6(const ushort* __restrict__ qb, const ushort* __restrict__ kb,
                                                const ushort* __restrict__ vtb, ushort* __restrict__ ob) {
    __shared__ ushort Qs[8192];          // [dc8][q128][8] 16KB
    __shared__ ushort Ks[3][4096];       // [dc8][kv64][8] 8KB x3
    __shared__ ushort Vs[3][4096];       // [kvc8][d64][8] 8KB x3
    int flat = blockIdx.x;
    int swz = (flat & 7) * 64 + (flat >> 3);           // XCD-chunked (512 % 8 == 0)
    int qt = swz & 15, h = (swz >> 4) & 15, b = swz >> 8;
    int t = threadIdx.x, l = t & 63, w = t >> 6;
    int ll = l & 31, hi = l >> 5;
    const ushort* Qg = qb + (size_t)b * NQ * INNER + h * DH;
    const ushort* Kg = kb + (size_t)b * NKV * INNER + h * DH;
    const ushort* Vg = vtb + (((size_t)b * HEADS + h) * DH) * NKV;
    int q0 = qt * 128;

    // stage Q (16 segments of 1KB, 4 per wave)
#pragma unroll
    for (int i = 0; i < 4; i++) {
        int s = w * 4 + i;
        gload16(Qg + (size_t)(q0 + (s & 1) * 64 + l) * INNER + (s >> 1) * 8, &Qs[s * 512]);
    }
    auto stageKV = [&](int buf, int kv0) {
#pragma unroll
        for (int i = 0; i < 2; i++) {
            int s = w + i * 4;
            gload16(Kg + (size_t)(kv0 + l) * INNER + s * 8, &Ks[buf][s * 512]);
            gload16(Vg + (size_t)l * NKV + kv0 + s * 8, &Vs[buf][s * 512]);
        }
    };
    stageKV(0, 0);
    stageKV(1, 64);
    asm volatile("s_waitcnt vmcnt(8)" ::: "memory");   // Q landed (stage0/1 may be in flight)
    __builtin_amdgcn_s_barrier();
    asm volatile("" ::: "memory");

    // Q B-fragments for 32x32x16: lane: q col = w*32+ll, k rows d = dchunk*16 + hi*8 + 0..7
    bf16x8 qf[4];
#pragma unroll
    for (int dchunk = 0; dchunk < 4; dchunk++) {
        int dc = dchunk * 2 + hi;
        qf[dchunk] = *(const bf16x8*)&Qs[(dc * 128 + w * 32 + ll) * 8];
    }

    f32x16 o0 = {}, o1 = {};             // O^T dblk 0/1: col q = w*32+ll, rows d per 32x32 D-layout
    float m_ = -1e30f, s_ = 0.f;

    constexpr int NT2 = NKV / 64;        // 32
    for (int tt = 0; tt < NT2; ++tt) {
        int cur = tt % 3;
        if (tt + 1 < NT2) {
            asm volatile("s_waitcnt vmcnt(4)" ::: "memory");   // tile tt landed
        } else {
            asm volatile("s_waitcnt vmcnt(0)" ::: "memory");
        }
        __builtin_amdgcn_s_barrier();
        asm volatile("" ::: "memory");
        if (tt + 2 < NT2) stageKV((tt + 2) % 3, (tt + 2) * 64);   // after barrier: buf (tt+2)%3 is free

        // QK^T: S^T[kv64][q32] via 2 kv-blocks x 4 d-chunks of mfma_32x32x16
        f32x16 st0 = {}, st1 = {};
        __builtin_amdgcn_s_setprio(1);
#pragma unroll
        for (int dchunk = 0; dchunk < 4; dchunk++) {
            int dc = dchunk * 2 + hi;
            bf16x8 kf0 = *(const bf16x8*)&Ks[cur][(dc * 64 + ll) * 8];
            bf16x8 kf1 = *(const bf16x8*)&Ks[cur][(dc * 64 + 32 + ll) * 8];
            st0 = __builtin_amdgcn_mfma_f32_32x32x16_bf16(kf0, qf[dchunk], st0, 0, 0, 0);
            st1 = __builtin_amdgcn_mfma_f32_32x32x16_bf16(kf1, qf[dchunk], st1, 0, 0, 0);
        }
        __builtin_amdgcn_s_setprio(0);

        // in-register online softmax: lane owns q; kv rows split between lane l and l^32
        float mx = st0[0];
#pragma unroll
        for (int r = 1; r < 16; r++) mx = fmaxf(mx, st0[r]);
#pragma unroll
        for (int r = 0; r < 16; r++) mx = fmaxf(mx, st1[r]);
        mx = fmaxf(mx, __shfl_xor(mx, 32));
        if (!__all(mx - m_ <= 8.f)) {        // defer-max (T13)
            float mn = fmaxf(m_, mx);
            float fac = __builtin_amdgcn_exp2f(m_ - mn);
            m_ = mn;
            s_ *= fac;
            o0 *= fac;
            o1 *= fac;
        }
        float mn = m_;
        float pp[32];
        float rs = 0.f;
#pragma unroll
        for (int r = 0; r < 16; r++) { pp[r] = __builtin_amdgcn_exp2f(st0[r] - mn); rs += pp[r]; }
#pragma unroll
        for (int r = 0; r < 16; r++) { pp[16 + r] = __builtin_amdgcn_exp2f(st1[r] - mn); rs += pp[16 + r]; }
        rs += __shfl_xor(rs, 32);
        s_ += rs;

        // P -> PV B-fragments fully in registers: cvt_pk pairs + permlane32_swap row exchange.
        bf16x8 pb[4];
#pragma unroll
        for (int kvb = 0; kvb < 2; kvb++)
#pragma unroll
            for (int c = 0; c < 2; c++) {
                int base = kvb * 16 + c * 8;
                uint a0 = pkbf16(pp[base + 0], pp[base + 1]);   // rows 16c+(0,1)+4hi
                uint a1 = pkbf16(pp[base + 2], pp[base + 3]);   // rows 16c+(2,3)+4hi
                uint b0 = pkbf16(pp[base + 4], pp[base + 5]);   // rows 16c+(8,9)+4hi
                uint b1 = pkbf16(pp[base + 6], pp[base + 7]);   // rows 16c+(10,11)+4hi
                asm volatile("v_permlane32_swap_b32 %0, %1" : "+v"(a0), "+v"(b0));
                asm volatile("v_permlane32_swap_b32 %0, %1" : "+v"(a1), "+v"(b1));
                u32x4 wrd = {a0, a1, b0, b1};   // lane<32: rows (0,1),(2,3),(4,5),(6,7); lane>=32: (8,9)..(14,15)
                pb[kvb * 2 + c] = __builtin_bit_cast(bf16x8, wrd);
            }

        // PV: O^T[d][q] += V^T-frag x P-frag over 4 kv-chunks
        __builtin_amdgcn_s_setprio(1);
#pragma unroll
        for (int kvchunk = 0; kvchunk < 4; kvchunk++) {
            int kvc = kvchunk * 2 + hi;
            bf16x8 vf0 = *(const bf16x8*)&Vs[cur][(kvc * 64 + ll) * 8];
            bf16x8 vf1 = *(const bf16x8*)&Vs[cur][(kvc * 64 + 32 + ll) * 8];
            o0 = __builtin_amdgcn_mfma_f32_32x32x16_bf16(vf0, pb[kvchunk], o0, 0, 0, 0);
            o1 = __builtin_amdgcn_mfma_f32_32x32x16_bf16(vf1, pb[kvchunk], o1, 0, 0, 0);
        }
        __builtin_amdgcn_s_setprio(0);
    }

    ushort* Og = ob + (size_t)b * NQ * INNER + h * DH;
    float inv = 1.f / s_;
    int q = q0 + w * 32 + ll;
#pragma unroll
    for (int rq = 0; rq < 4; rq++) {
        int d0 = 8 * rq + 4 * hi;
        uint2 pw;
        pw.x = pkbf16(o0[4 * rq + 0] * inv, o0[4 * rq + 1] * inv);
        pw.y = pkbf16(o0[4 * rq + 2] * inv, o0[4 * rq + 3] * inv);
        *(uint2*)&Og[(size_t)q * INNER + d0] = pw;
        uint2 pw1;
        pw1.x = pkbf16(o1[4 * rq + 0] * inv, o1[4 * rq + 1] * inv);
        pw1.y = pkbf16(o1[4 * rq + 2] * inv, o1[4 * rq + 3] * inv);
        *(uint2*)&Og[(size_t)q * INNER + 32 + d0] = pw1;
    }
}

extern "C" void kernel_launch(void* const* d_in, const int* in_sizes, int n_in,
                              void* d_out, int out_size, void* d_ws, size_t ws_size,
                              hipStream_t stream) {
    const float* x    = (const float*)d_in[0];
    const float* ctx  = (const float*)d_in[1];
    const float* Wq   = (const float*)d_in[2];
    const float* Wkv  = (const float*)d_in[3];
    const float* Wout = (const float*)d_in[4];
    const float* bout = (const float*)d_in[5];
    float* out = (float*)d_out;

    if (ws_size < (size_t)(56u << 20)) return;  // need 56MB scratch
    char* ws = (char*)d_ws;
    ushort* xb    = (ushort*)(ws);                 // 8MB
    ushort* cb    = (ushort*)(ws + (8u << 20));    // 8MB, dead after gemm_qkv
    ushort* ob    = (ushort*)(ws + (8u << 20));    // reuse cb slot
    ushort* qb    = (ushort*)(ws + (16u << 20));
    ushort* kb    = (ushort*)(ws + (24u << 20));
    ushort* vtb   = (ushort*)(ws + (32u << 20));   // v written directly transposed
    ushort* Wqt   = (ushort*)(ws + (48u << 20));
    ushort* Wkvt  = (ushort*)(ws + (50u << 20));
    ushort* Woutt = (ushort*)(ws + (54u << 20));

    prep<<<dim3(32, 32, 5), dim3(32, 8), 0, stream>>>(x, ctx, Wq, Wkv, Wout, xb, cb, Wqt, Wkvt, Woutt);
    // fused q-proj (scaled by 0.125*log2e) + kv-proj (v written transposed)
    gemm_qkv<<<768, 256, 0, stream>>>(xb, cb, Wqt, Wkvt, qb, kb, vtb, 0.125f * 1.44269504f);
    attn6<<<512, 256, 0, stream>>>(qb, kb, vtb, ob);
    gemm_out<<<512, 256, 0, stream>>>(ob, Woutt, out, bout);
}

// Round 21
// 160.703 us; speedup vs baseline: 1.0729x; 1.0278x over previous
//
#include <hip/hip_runtime.h>
#include <hip/hip_bf16.h>
#include <stdint.h>

#define NQ 2048
#define NKV 2048
#define DIM 1024
#define INNER 1024
#define HEADS 16
#define DH 64
#define BATCH 2

typedef float f32x4 __attribute__((ext_vector_type(4)));
typedef float f32x16 __attribute__((ext_vector_type(16)));
typedef __bf16 bf16x8 __attribute__((ext_vector_type(8)));
typedef unsigned int u32x4 __attribute__((ext_vector_type(4)));

__device__ inline ushort f2b(float f) {
    uint32_t u = __builtin_bit_cast(uint32_t, f);
    u += 0x7fff + ((u >> 16) & 1);   // round-to-nearest-even
    return (ushort)(u >> 16);
}

__device__ inline uint pkbf16(float lo, float hi) {
    __hip_bfloat162 h = __float22bfloat162_rn(make_float2(lo, hi));
    uint r;
    __builtin_memcpy(&r, &h, 4);   // low 16 = bf16(lo), high 16 = bf16(hi)
    return r;
}

__device__ __forceinline__ void gload16(const void* g, void* lds) {
    __builtin_amdgcn_global_load_lds(
        (const __attribute__((address_space(1))) unsigned int*)g,
        (__attribute__((address_space(3))) unsigned int*)lds, 16, 0, 0);
}

// ---------------- fused prep: z<4 -> weight transpose+cvt slices; z==4 -> x/ctx convert ----------------
__global__ void prep(const float* __restrict__ x, const float* __restrict__ ctx,
                     const float* __restrict__ Wq, const float* __restrict__ Wkv,
                     const float* __restrict__ Wout,
                     ushort* __restrict__ xb, ushort* __restrict__ cb,
                     ushort* __restrict__ Wqt, ushort* __restrict__ Wkvt,
                     ushort* __restrict__ Woutt) {
    int z = blockIdx.z;
    if (z < 4) {
        __shared__ ushort tile[32][33];
        const float* src; ushort* dst; int C;
        if (z == 0)      { src = Wq;          dst = Wqt;                C = 1024; }
        else if (z == 1) { src = Wkv;         dst = Wkvt;               C = 2048; }
        else if (z == 2) { src = Wkv + 1024;  dst = Wkvt + 1024 * 1024; C = 2048; }
        else             { src = Wout;        dst = Woutt;              C = 1024; }
        int c0 = blockIdx.x * 32, r0 = blockIdx.y * 32;
        int tx = threadIdx.x, ty = threadIdx.y;   // 32 x 8
#pragma unroll
        for (int i = 0; i < 4; i++)
            tile[ty + i * 8][tx] = f2b(src[(size_t)(r0 + ty + i * 8) * C + c0 + tx]);
        __syncthreads();
#pragma unroll
        for (int i = 0; i < 4; i++)
            dst[(size_t)(c0 + ty + i * 8) * 1024 + r0 + tx] = tile[tx][ty + i * 8];
    } else {
        const int n4 = (BATCH * NQ * DIM) / 4;   // float4 count per tensor
        int fb = blockIdx.y * 32 + blockIdx.x;   // 0..1023
        int t = threadIdx.y * 32 + threadIdx.x;  // 0..255
        for (int i = fb * 256 + t; i < 2 * n4; i += 1024 * 256) {
            float4 v;
            if (i < n4) v = ((const float4*)x)[i];
            else        v = ((const float4*)ctx)[i - n4];
            ushort4 o;
            o.x = f2b(v.x); o.y = f2b(v.y); o.z = f2b(v.z); o.w = f2b(v.w);
            if (i < n4) ((ushort4*)xb)[i] = o;
            else        ((ushort4*)cb)[i - n4] = o;
        }
    }
}

// ---------------- fused q/kv GEMM: 768 blocks of 128x128, K=1024, triple-buffer 2-deep prefetch ----------------
__global__ __launch_bounds__(256) void gemm_qkv(const ushort* __restrict__ xb, const ushort* __restrict__ cb,
                                                const ushort* __restrict__ Wqt, const ushort* __restrict__ Wkvt,
                                                ushort* __restrict__ qb, ushort* __restrict__ kb,
                                                ushort* __restrict__ vtb, float qscale) {
    constexpr int K = 1024, NT = 32;
    __shared__ ushort lds[24576];   // 48KB: 3 bufs x (A 8KB + B 8KB); v-epilogue tile [128][136] reuses
    int flat = blockIdx.x;
    int swz = (flat & 7) * 96 + (flat >> 3);      // XCD-chunked, bijective (768 % 8 == 0)
    bool isq = swz < 256;
    const ushort *A, *Bt;
    int m0, n0;
    if (isq) { A = xb; Bt = Wqt;  m0 = (swz >> 3) * 128;  n0 = (swz & 7) * 128; }
    else     { int b2 = swz - 256; A = cb; Bt = Wkvt; m0 = (b2 >> 4) * 128; n0 = (b2 & 15) * 128; }
    int t = threadIdx.x, l = t & 63, w = t >> 6;
    int wr = w >> 1, wc = w & 1;
    int lg = l >> 4, lc = l & 15;
    f32x4 acc[4][4] = {};

    auto stage = [&](int buf, int k0) {
#pragma unroll
        for (int i = 0; i < 2; i++) {
            int s = w + i * 4;
            gload16(A + (size_t)(m0 + (s & 1) * 64 + l) * K + k0 + (s >> 1) * 8, &lds[buf * 8192 + s * 512]);
            gload16(Bt + (size_t)(n0 + (s & 1) * 64 + l) * K + k0 + (s >> 1) * 8, &lds[buf * 8192 + 4096 + s * 512]);
        }
    };

    stage(0, 0);
    stage(1, 32);
    for (int tt = 0; tt < NT; ++tt) {
        int cur = tt % 3;
        if (tt + 2 < NT) {
            stage((tt + 2) % 3, (tt + 2) * 32);   // 2-deep prefetch, stays in flight
            asm volatile("s_waitcnt vmcnt(8)" ::: "memory");   // oldest 4 (cur tile) done
        } else if (tt + 1 < NT) {
            asm volatile("s_waitcnt vmcnt(4)" ::: "memory");
        } else {
            asm volatile("s_waitcnt vmcnt(0)" ::: "memory");
        }
        __builtin_amdgcn_s_barrier();
        asm volatile("" ::: "memory");
        bf16x8 af[4], bf[4];
#pragma unroll
        for (int mi = 0; mi < 4; mi++)
            af[mi] = *(const bf16x8*)&lds[cur * 8192 + (lg * 128 + wr * 64 + mi * 16 + lc) * 8];
#pragma unroll
        for (int ni = 0; ni < 4; ni++)
            bf[ni] = *(const bf16x8*)&lds[cur * 8192 + 4096 + (lg * 128 + wc * 64 + ni * 16 + lc) * 8];
        __builtin_amdgcn_s_setprio(1);
#pragma unroll
        for (int mi = 0; mi < 4; mi++)
#pragma unroll
            for (int ni = 0; ni < 4; ni++)
                acc[mi][ni] = __builtin_amdgcn_mfma_f32_16x16x32_bf16(af[mi], bf[ni], acc[mi][ni], 0, 0, 0);
        __builtin_amdgcn_s_setprio(0);
        asm volatile("s_waitcnt lgkmcnt(0)" ::: "memory");
        __builtin_amdgcn_s_barrier();
        asm volatile("" ::: "memory");
    }
    if (isq) {
#pragma unroll
        for (int mi = 0; mi < 4; mi++)
#pragma unroll
            for (int ni = 0; ni < 4; ni++)
#pragma unroll
                for (int r = 0; r < 4; r++) {
                    int m = m0 + wr * 64 + mi * 16 + lg * 4 + r;
                    int n = n0 + wc * 64 + ni * 16 + lc;
                    qb[(size_t)m * 1024 + n] = f2b(acc[mi][ni][r] * qscale);
                }
    } else if (n0 < 1024) {      // k half: row-major
#pragma unroll
        for (int mi = 0; mi < 4; mi++)
#pragma unroll
            for (int ni = 0; ni < 4; ni++)
#pragma unroll
                for (int r = 0; r < 4; r++) {
                    int m = m0 + wr * 64 + mi * 16 + lg * 4 + r;
                    int n = n0 + wc * 64 + ni * 16 + lc;
                    kb[(size_t)m * 1024 + n] = f2b(acc[mi][ni][r]);
                }
    } else {                     // v half: LDS transpose -> coalesced vtb[b][h][d][kv] stores
        int b = m0 >> 11, kv0 = m0 & 2047;
        int h0 = (n0 - 1024) >> 6;                // block covers heads h0, h0+1
#pragma unroll
        for (int mi = 0; mi < 4; mi++)
#pragma unroll
            for (int ni = 0; ni < 4; ni++)
#pragma unroll
                for (int r = 0; r < 4; r++) {
                    int ml = wr * 64 + mi * 16 + lg * 4 + r;    // kv-local 0..127
                    int nl = wc * 64 + ni * 16 + lc;            // n-local 0..127
                    lds[nl * 136 + ml] = f2b(acc[mi][ni][r]);
                }
        __syncthreads();
#pragma unroll
        for (int c = 0; c < 8; c++) {
            int idx = c * 256 + t;            // 0..2047
            int rrow = idx >> 4;              // n-local 0..127
            int chunk = idx & 15;             // 16B chunk along kv
            int h = h0 + (rrow >> 6), d = rrow & 63;
            u32x4 v = *(u32x4*)&lds[rrow * 136 + chunk * 8];
            *(u32x4*)&vtb[(((size_t)b * HEADS + h) * DH + d) * (size_t)NKV + kv0 + chunk * 8] = v;
        }
    }
}

// ---------------- out-proj GEMM: 256 blocks of 128x128, triple-buffer 2-deep, f32 out + bias ----------------
__global__ __launch_bounds__(256) void gemm_out(const ushort* __restrict__ A, const ushort* __restrict__ Bt,
                                                float* __restrict__ C0, const float* __restrict__ bias) {
    constexpr int K = 1024, NT = 32;
    __shared__ ushort lds[24576];
    int flat = blockIdx.x;
    int swz = (flat & 7) * 32 + (flat >> 3);      // XCD-chunked (256 % 8 == 0)
    int m0 = (swz >> 3) * 128, n0 = (swz & 7) * 128;
    int t = threadIdx.x, l = t & 63, w = t >> 6;
    int wr = w >> 1, wc = w & 1;
    int lg = l >> 4, lc = l & 15;
    f32x4 acc[4][4] = {};

    auto stage = [&](int buf, int k0) {
#pragma unroll
        for (int i = 0; i < 2; i++) {
            int s = w + i * 4;
            gload16(A + (size_t)(m0 + (s & 1) * 64 + l) * K + k0 + (s >> 1) * 8, &lds[buf * 8192 + s * 512]);
            gload16(Bt + (size_t)(n0 + (s & 1) * 64 + l) * K + k0 + (s >> 1) * 8, &lds[buf * 8192 + 4096 + s * 512]);
        }
    };

    stage(0, 0);
    stage(1, 32);
    for (int tt = 0; tt < NT; ++tt) {
        int cur = tt % 3;
        if (tt + 2 < NT) {
            stage((tt + 2) % 3, (tt + 2) * 32);
            asm volatile("s_waitcnt vmcnt(8)" ::: "memory");
        } else if (tt + 1 < NT) {
            asm volatile("s_waitcnt vmcnt(4)" ::: "memory");
        } else {
            asm volatile("s_waitcnt vmcnt(0)" ::: "memory");
        }
        __builtin_amdgcn_s_barrier();
        asm volatile("" ::: "memory");
        bf16x8 af[4], bf[4];
#pragma unroll
        for (int mi = 0; mi < 4; mi++)
            af[mi] = *(const bf16x8*)&lds[cur * 8192 + (lg * 128 + wr * 64 + mi * 16 + lc) * 8];
#pragma unroll
        for (int ni = 0; ni < 4; ni++)
            bf[ni] = *(const bf16x8*)&lds[cur * 8192 + 4096 + (lg * 128 + wc * 64 + ni * 16 + lc) * 8];
        __builtin_amdgcn_s_setprio(1);
#pragma unroll
        for (int mi = 0; mi < 4; mi++)
#pragma unroll
            for (int ni = 0; ni < 4; ni++)
                acc[mi][ni] = __builtin_amdgcn_mfma_f32_16x16x32_bf16(af[mi], bf[ni], acc[mi][ni], 0, 0, 0);
        __builtin_amdgcn_s_setprio(0);
        asm volatile("s_waitcnt lgkmcnt(0)" ::: "memory");
        __builtin_amdgcn_s_barrier();
        asm volatile("" ::: "memory");
    }
#pragma unroll
    for (int mi = 0; mi < 4; mi++)
#pragma unroll
        for (int ni = 0; ni < 4; ni++)
#pragma unroll
            for (int r = 0; r < 4; r++) {
                int m = m0 + wr * 64 + mi * 16 + lg * 4 + r;
                int n = n0 + wc * 64 + ni * 16 + lc;
                C0[(size_t)m * 1024 + n] = acc[mi][ni][r] + bias[n];
            }
}

// ---------------- flash attention v8 (R15-proven): 32x32 MFMA, in-register P, 3-buffer K/V ----------------
// QBLK=128 (4 waves x 32 q each), KVBLK=64, triple-buffered K/V with 2-deep prefetch.
// Swapped QK^T: S^T[kv][q], lane owns q = w*32 + (l&31). NO P-LDS roundtrip. qb pre-scaled 0.125*log2e.
__global__ __launch_bounds__(256, 2) void attn6(const ushort* __restrict__ qb, const ushort* __restrict__ kb,
                                                const ushort* __restrict__ vtb, ushort* __restrict__ ob) {
    __shared__ ushort Qs[8192];          // [dc8][q128][8] 16KB
    __shared__ ushort Ks[3][4096];       // [dc8][kv64][8] 8KB x3
    __shared__ ushort Vs[3][4096];       // [kvc8][d64][8] 8KB x3
    int flat = blockIdx.x;
    int swz = (flat & 7) * 64 + (flat >> 3);           // XCD-chunked (512 % 8 == 0)
    int qt = swz & 15, h = (swz >> 4) & 15, b = swz >> 8;
    int t = threadIdx.x, l = t & 63, w = t >> 6;
    int ll = l & 31, hi = l >> 5;
    const ushort* Qg = qb + (size_t)b * NQ * INNER + h * DH;
    const ushort* Kg = kb + (size_t)b * NKV * INNER + h * DH;
    const ushort* Vg = vtb + (((size_t)b * HEADS + h) * DH) * NKV;
    int q0 = qt * 128;

    // stage Q (16 segments of 1KB, 4 per wave)
#pragma unroll
    for (int i = 0; i < 4; i++) {
        int s = w * 4 + i;
        gload16(Qg + (size_t)(q0 + (s & 1) * 64 + l) * INNER + (s >> 1) * 8, &Qs[s * 512]);
    }
    auto stageKV = [&](int buf, int kv0) {
#pragma unroll
        for (int i = 0; i < 2; i++) {
            int s = w + i * 4;
            gload16(Kg + (size_t)(kv0 + l) * INNER + s * 8, &Ks[buf][s * 512]);
            gload16(Vg + (size_t)l * NKV + kv0 + s * 8, &Vs[buf][s * 512]);
        }
    };
    stageKV(0, 0);
    stageKV(1, 64);
    asm volatile("s_waitcnt vmcnt(8)" ::: "memory");   // Q landed (stage0/1 may be in flight)
    __builtin_amdgcn_s_barrier();
    asm volatile("" ::: "memory");

    // Q B-fragments for 32x32x16: lane: q col = w*32+ll, k rows d = dchunk*16 + hi*8 + 0..7
    bf16x8 qf[4];
#pragma unroll
    for (int dchunk = 0; dchunk < 4; dchunk++) {
        int dc = dchunk * 2 + hi;
        qf[dchunk] = *(const bf16x8*)&Qs[(dc * 128 + w * 32 + ll) * 8];
    }

    f32x16 o0 = {}, o1 = {};             // O^T dblk 0/1: col q = w*32+ll, rows d per 32x32 D-layout
    float m_ = -1e30f, s_ = 0.f;

    constexpr int NT2 = NKV / 64;        // 32
    for (int tt = 0; tt < NT2; ++tt) {
        int cur = tt % 3;
        if (tt + 1 < NT2) {
            asm volatile("s_waitcnt vmcnt(4)" ::: "memory");   // tile tt landed
        } else {
            asm volatile("s_waitcnt vmcnt(0)" ::: "memory");
        }
        __builtin_amdgcn_s_barrier();
        asm volatile("" ::: "memory");
        if (tt + 2 < NT2) stageKV((tt + 2) % 3, (tt + 2) * 64);   // after barrier: buf (tt+2)%3 is free

        // QK^T: S^T[kv64][q32] via 2 kv-blocks x 4 d-chunks of mfma_32x32x16
        f32x16 st0 = {}, st1 = {};
        __builtin_amdgcn_s_setprio(1);
#pragma unroll
        for (int dchunk = 0; dchunk < 4; dchunk++) {
            int dc = dchunk * 2 + hi;
            bf16x8 kf0 = *(const bf16x8*)&Ks[cur][(dc * 64 + ll) * 8];
            bf16x8 kf1 = *(const bf16x8*)&Ks[cur][(dc * 64 + 32 + ll) * 8];
            st0 = __builtin_amdgcn_mfma_f32_32x32x16_bf16(kf0, qf[dchunk], st0, 0, 0, 0);
            st1 = __builtin_amdgcn_mfma_f32_32x32x16_bf16(kf1, qf[dchunk], st1, 0, 0, 0);
        }
        __builtin_amdgcn_s_setprio(0);

        // in-register online softmax: lane owns q; kv rows split between lane l and l^32
        float mx = st0[0];
#pragma unroll
        for (int r = 1; r < 16; r++) mx = fmaxf(mx, st0[r]);
#pragma unroll
        for (int r = 0; r < 16; r++) mx = fmaxf(mx, st1[r]);
        mx = fmaxf(mx, __shfl_xor(mx, 32));
        if (!__all(mx - m_ <= 8.f)) {        // defer-max (T13)
            float mn = fmaxf(m_, mx);
            float fac = __builtin_amdgcn_exp2f(m_ - mn);
            m_ = mn;
            s_ *= fac;
            o0 *= fac;
            o1 *= fac;
        }
        float mn = m_;
        float pp[32];
        float rs = 0.f;
#pragma unroll
        for (int r = 0; r < 16; r++) { pp[r] = __builtin_amdgcn_exp2f(st0[r] - mn); rs += pp[r]; }
#pragma unroll
        for (int r = 0; r < 16; r++) { pp[16 + r] = __builtin_amdgcn_exp2f(st1[r] - mn); rs += pp[16 + r]; }
        rs += __shfl_xor(rs, 32);
        s_ += rs;

        // P -> PV B-fragments fully in registers: cvt_pk pairs + permlane32_swap row exchange.
        bf16x8 pb[4];
#pragma unroll
        for (int kvb = 0; kvb < 2; kvb++)
#pragma unroll
            for (int c = 0; c < 2; c++) {
                int base = kvb * 16 + c * 8;
                uint a0 = pkbf16(pp[base + 0], pp[base + 1]);   // rows 16c+(0,1)+4hi
                uint a1 = pkbf16(pp[base + 2], pp[base + 3]);   // rows 16c+(2,3)+4hi
                uint b0 = pkbf16(pp[base + 4], pp[base + 5]);   // rows 16c+(8,9)+4hi
                uint b1 = pkbf16(pp[base + 6], pp[base + 7]);   // rows 16c+(10,11)+4hi
                asm volatile("v_permlane32_swap_b32 %0, %1" : "+v"(a0), "+v"(b0));
                asm volatile("v_permlane32_swap_b32 %0, %1" : "+v"(a1), "+v"(b1));
                u32x4 wrd = {a0, a1, b0, b1};   // lane<32: rows (0,1),(2,3),(4,5),(6,7); lane>=32: (8,9)..(14,15)
                pb[kvb * 2 + c] = __builtin_bit_cast(bf16x8, wrd);
            }

        // PV: O^T[d][q] += V^T-frag x P-frag over 4 kv-chunks
        __builtin_amdgcn_s_setprio(1);
#pragma unroll
        for (int kvchunk = 0; kvchunk < 4; kvchunk++) {
            int kvc = kvchunk * 2 + hi;
            bf16x8 vf0 = *(const bf16x8*)&Vs[cur][(kvc * 64 + ll) * 8];
            bf16x8 vf1 = *(const bf16x8*)&Vs[cur][(kvc * 64 + 32 + ll) * 8];
            o0 = __builtin_amdgcn_mfma_f32_32x32x16_bf16(vf0, pb[kvchunk], o0, 0, 0, 0);
            o1 = __builtin_amdgcn_mfma_f32_32x32x16_bf16(vf1, pb[kvchunk], o1, 0, 0, 0);
        }
        __builtin_amdgcn_s_setprio(0);
    }

    ushort* Og = ob + (size_t)b * NQ * INNER + h * DH;
    float inv = 1.f / s_;
    int q = q0 + w * 32 + ll;
#pragma unroll
    for (int rq = 0; rq < 4; rq++) {
        int d0 = 8 * rq + 4 * hi;
        uint2 pw;
        pw.x = pkbf16(o0[4 * rq + 0] * inv, o0[4 * rq + 1] * inv);
        pw.y = pkbf16(o0[4 * rq + 2] * inv, o0[4 * rq + 3] * inv);
        *(uint2*)&Og[(size_t)q * INNER + d0] = pw;
        uint2 pw1;
        pw1.x = pkbf16(o1[4 * rq + 0] * inv, o1[4 * rq + 1] * inv);
        pw1.y = pkbf16(o1[4 * rq + 2] * inv, o1[4 * rq + 3] * inv);
        *(uint2*)&Og[(size_t)q * INNER + 32 + d0] = pw1;
    }
}

extern "C" void kernel_launch(void* const* d_in, const int* in_sizes, int n_in,
                              void* d_out, int out_size, void* d_ws, size_t ws_size,
                              hipStream_t stream) {
    const float* x    = (const float*)d_in[0];
    const float* ctx  = (const float*)d_in[1];
    const float* Wq   = (const float*)d_in[2];
    const float* Wkv  = (const float*)d_in[3];
    const float* Wout = (const float*)d_in[4];
    const float* bout = (const float*)d_in[5];
    float* out = (float*)d_out;

    if (ws_size < (size_t)(56u << 20)) return;  // need 56MB scratch
    char* ws = (char*)d_ws;
    ushort* xb    = (ushort*)(ws);                 // 8MB
    ushort* cb    = (ushort*)(ws + (8u << 20));    // 8MB, dead after gemm_qkv
    ushort* ob    = (ushort*)(ws + (8u << 20));    // reuse cb slot
    ushort* qb    = (ushort*)(ws + (16u << 20));
    ushort* kb    = (ushort*)(ws + (24u << 20));
    ushort* vtb   = (ushort*)(ws + (32u << 20));   // v written directly transposed
    ushort* Wqt   = (ushort*)(ws + (48u << 20));
    ushort* Wkvt  = (ushort*)(ws + (50u << 20));
    ushort* Woutt = (ushort*)(ws + (54u << 20));

    prep<<<dim3(32, 32, 5), dim3(32, 8), 0, stream>>>(x, ctx, Wq, Wkv, Wout, xb, cb, Wqt, Wkvt, Woutt);
    // fused q-proj (scaled by 0.125*log2e) + kv-proj (v written transposed)
    gemm_qkv<<<768, 256, 0, stream>>>(xb, cb, Wqt, Wkvt, qb, kb, vtb, 0.125f * 1.44269504f);
    attn6<<<512, 256, 0, stream>>>(qb, kb, vtb, ob);
    gemm_out<<<256, 256, 0, stream>>>(ob, Woutt, out, bout);
}